// Round 13
// baseline (40.881 us; speedup 1.0000x reference)
//
#include <hip/hip_runtime.h>

// Modulated deformable depthwise conv, B=8 C=128 H=W=64 K=3 PAD=1 STRIDE=1.
// Round 12: unlock the 5th block/CU. VGPR=108 -> floor(512/108)=4 waves/SIMD
// (16 waves/CU); <=102 gives 5 blocks/CU (20 waves, +25% TLP). Re-apply the
// H1/H2 staging split (peak staging regs 24->12; safe now that round 10
// hoisted the corrective path out of the liveness peak). Iteration order:
// corrective(execz) -> H1 load -> tap loop (hides H1) -> H2 load -> stores
// (hide H2) -> barrier -> write A+B -> barrier. All else = round 11.

#define BB 8
#define CC 128
#define HH 64
#define WW 64
#define HWs (HH*WW)
#define KKT 9
#define CH 16              // channels per block
#define NCG (CC/CH)        // 8
#define CPI 4              // channels per LDS float4 cell
#define NIT (CH/CPI)       // 4
#define ROWS 4             // output rows per block
#define NHS (HH/ROWS)      // 16
#define WLO 6
#define WR  (ROWS+14)      // 18 staged rows
#define CLO 6
#define WC  76
#define CELLS (WR*WC)      // 1368 float4 cells = 21.9 KB
#define NTHR 256
#define NK  ((CELLS + NTHR - 1)/NTHR)   // 6
#define NKH 3              // half of NK

__global__ __launch_bounds__(NTHR, 2)
void mdcn_kernel(const float* __restrict__ x,
                 const float* __restrict__ offset,
                 const float* __restrict__ mask,
                 const float* __restrict__ dynw,
                 float* __restrict__ out)
{
    __shared__ float4 lds[CELLS];

    const int blk = blockIdx.x;
    const int hs = blk & (NHS - 1);
    const int cg = (blk >> 4) & (NCG - 1);
    const int b  = blk >> 7;
    const int tid = threadIdx.x;
    const int w = tid & 63;
    const int h0 = hs * ROWS;
    const int h = h0 + (tid >> 6);

    const float* xg = x + (size_t)(b * CC + cg * CH) * HWs;

    float4 stgA[NKH];
    float4 stgB[NKH];

    #define LOAD_HALF(ARR, K0, XP)                                            \
    do {                                                                      \
        const float* xp_ = (XP);                                              \
        _Pragma("unroll")                                                     \
        for (int k = 0; k < NKH; ++k) {                                       \
            const int idx = tid + (k + (K0)) * NTHR;                          \
            float4 v = make_float4(0.f, 0.f, 0.f, 0.f);                       \
            if (idx < CELLS) {                                                \
                const int row = idx / WC;                                     \
                const int col = idx - row * WC - CLO;                         \
                const int ar  = h0 - WLO + row;                               \
                if ((unsigned)ar < (unsigned)HH &&                            \
                    (unsigned)col < (unsigned)WW) {                           \
                    const float* pp = xp_ + ar * WW + col;                    \
                    v.x = pp[0 * HWs]; v.y = pp[1 * HWs];                     \
                    v.z = pp[2 * HWs]; v.w = pp[3 * HWs];                     \
                }                                                             \
            }                                                                 \
            (ARR)[k] = v;                                                     \
        }                                                                     \
    } while (0)

    #define WRITE_HALF(ARR, K0)                                               \
    do {                                                                      \
        _Pragma("unroll")                                                     \
        for (int k = 0; k < NKH; ++k) {                                       \
            const int idx = tid + (k + (K0)) * NTHR;                          \
            if (idx < CELLS) lds[idx] = (ARR)[k];                             \
        }                                                                     \
    } while (0)

    // prologue: stage group 0 (both halves); metadata overlaps load latency
    LOAD_HALF(stgA, 0, xg);
    LOAD_HALF(stgB, NKH, xg);

    // ---- per-tap metadata: m, dy, dx + window offset (compact) ----
    float mv[KKT], dyv[KKT], dxv[KKT];
    int   woff[KKT];
    int   badmask = 0;
    const float* offp = offset + (size_t)b * (2 * KKT) * HWs + h * WW + w;
    const float* mskp = mask   + (size_t)b * KKT * HWs       + h * WW + w;
    #pragma unroll
    for (int t = 0; t < KKT; ++t) {
        const float oy = offp[(2 * t)     * HWs];
        const float ox = offp[(2 * t + 1) * HWs];
        const float m  = mskp[t * HWs];
        const float py = (float)(h - 1 + t / 3) + oy;
        const float px = (float)(w - 1 + t % 3) + ox;
        const float fy = floorf(py), fx = floorf(px);
        const int y0 = (int)fy, x0 = (int)fx;
        dyv[t] = py - fy;
        dxv[t] = px - fx;
        const bool inwin = (y0 >= h0 - WLO) && (y0 <= h0 - WLO + WR - 2) &&
                           (x0 >= -CLO)     && (x0 <= -CLO + WC - 2);
        if (!inwin) {
            badmask |= (1 << t);
            woff[t] = 0;
            mv[t] = 0.f;               // zeroes the LDS contribution
        } else {
            woff[t] = (y0 - (h0 - WLO)) * WC + (x0 + CLO);
            mv[t] = m;                 // pads hold zeros -> no corner masks
        }
    }
    const int anybad = __any(badmask != 0);

    WRITE_HALF(stgA, 0);
    WRITE_HALF(stgB, NKH);
    __syncthreads();

    const float* wtb  = dynw + (size_t)(b * CC + cg * CH) * KKT;
    float*       outp = out  + (size_t)(b * CC + cg * CH) * HWs + h * WW + w;

    for (int it = 0; it < NIT; ++it) {
        const float* wt = wtb + it * CPI * KKT;
        float s0 = 0.f, s1 = 0.f, s2 = 0.f, s3 = 0.f;

        // corrective path FIRST (staging regs not live; execz-skipped)
        if (anybad) {
            #pragma unroll
            for (int t = 0; t < KKT; ++t) {
                if (badmask & (1 << t)) {
                    const float oy = offp[(2 * t)     * HWs];
                    const float ox = offp[(2 * t + 1) * HWs];
                    const float m  = mskp[t * HWs];
                    const float py = (float)(h - 1 + t / 3) + oy;
                    const float px = (float)(w - 1 + t % 3) + ox;
                    const float fy = floorf(py), fx = floorf(px);
                    const float dy = py - fy, dx = px - fx;
                    const int y0 = (int)fy, x0 = (int)fx;
                    const int y1 = y0 + 1,  x1 = x0 + 1;
                    const int cy0 = min(max(y0, 0), HH - 1);
                    const int cy1 = min(max(y1, 0), HH - 1);
                    const int cx0 = min(max(x0, 0), WW - 1);
                    const int cx1 = min(max(x1, 0), WW - 1);
                    const float m00 = ((unsigned)y0 < HH && (unsigned)x0 < WW) ? 1.f : 0.f;
                    const float m01 = ((unsigned)y0 < HH && (unsigned)x1 < WW) ? 1.f : 0.f;
                    const float m10 = ((unsigned)y1 < HH && (unsigned)x0 < WW) ? 1.f : 0.f;
                    const float m11 = ((unsigned)y1 < HH && (unsigned)x1 < WW) ? 1.f : 0.f;
                    const float omdy = 1.f - dy, omdx = 1.f - dx;
                    #pragma unroll
                    for (int c = 0; c < CPI; ++c) {
                        const float* pl = xg + (size_t)(it * CPI + c) * HWs;
                        const float v = pl[cy0 * WW + cx0] * m00 * (omdy * omdx)
                                      + pl[cy0 * WW + cx1] * m01 * (omdy * dx)
                                      + pl[cy1 * WW + cx0] * m10 * (dy * omdx)
                                      + pl[cy1 * WW + cx1] * m11 * (dy * dx);
                        const float add = v * m * wt[c * KKT + t];
                        if      (c == 0) s0 += add;
                        else if (c == 1) s1 += add;
                        else if (c == 2) s2 += add;
                        else             s3 += add;
                    }
                }
            }
        }

        // H1 prefetch for next group (hidden under the tap loop)
        if (it + 1 < NIT) {
            LOAD_HALF(stgA, 0, xg + (size_t)(it + 1) * CPI * HWs);
        }

        #pragma unroll
        for (int t = 0; t < KKT; ++t) {
            const float4 c00 = lds[woff[t]];
            const float4 c01 = lds[woff[t] + 1];
            const float4 c10 = lds[woff[t] + WC];
            const float4 c11 = lds[woff[t] + WC + 1];
            const float dy = dyv[t], dx = dxv[t], m = mv[t];
            const float omdy = 1.f - dy, omdx = 1.f - dx;
            const float w00 = omdy * omdx * m, w01 = omdy * dx * m;
            const float w10 = dy * omdx * m,   w11 = dy * dx * m;
            const float v0 = c00.x * w00 + c01.x * w01 + c10.x * w10 + c11.x * w11;
            const float v1 = c00.y * w00 + c01.y * w01 + c10.y * w10 + c11.y * w11;
            const float v2 = c00.z * w00 + c01.z * w01 + c10.z * w10 + c11.z * w11;
            const float v3 = c00.w * w00 + c01.w * w01 + c10.w * w10 + c11.w * w11;
            s0 += v0 * wt[0 * KKT + t];
            s1 += v1 * wt[1 * KKT + t];
            s2 += v2 * wt[2 * KKT + t];
            s3 += v3 * wt[3 * KKT + t];
        }

        // H2 loads for next group (latency hidden under stores + barrier skew)
        if (it + 1 < NIT) {
            LOAD_HALF(stgB, NKH, xg + (size_t)(it + 1) * CPI * HWs);
        }

        outp[(size_t)(it * CPI + 0) * HWs] = s0;
        outp[(size_t)(it * CPI + 1) * HWs] = s1;
        outp[(size_t)(it * CPI + 2) * HWs] = s2;
        outp[(size_t)(it * CPI + 3) * HWs] = s3;

        if (it + 1 < NIT) {
            __syncthreads();       // all reads of the buffer done
            WRITE_HALF(stgA, 0);
            WRITE_HALF(stgB, NKH);
            __syncthreads();       // writes visible
        }
    }
    #undef LOAD_HALF
    #undef WRITE_HALF
}

extern "C" void kernel_launch(void* const* d_in, const int* in_sizes, int n_in,
                              void* d_out, int out_size, void* d_ws, size_t ws_size,
                              hipStream_t stream) {
    const float* x      = (const float*)d_in[0];
    const float* offset = (const float*)d_in[1];
    const float* mask   = (const float*)d_in[2];
    const float* dynw   = (const float*)d_in[3];
    float* out = (float*)d_out;

    dim3 grid(BB * NCG * NHS);   // 8 * 8 * 16 = 1024 blocks
    dim3 block(NTHR);
    mdcn_kernel<<<grid, block, 0, stream>>>(x, offset, mask, dynw, out);
}

// Round 14
// 34.970 us; speedup vs baseline: 1.1691x; 1.1691x over previous
//
#include <hip/hip_runtime.h>

// Modulated deformable depthwise conv, B=8 C=128 H=W=64 K=3 PAD=1 STRIDE=1.
// Round 13: combine round 10's 1-barrier double buffer with round 11's
// 4 blocks/CU by shrinking the window margin 6->5 (|off|<~4, 4sigma;
// out-of-window taps fall to the EXACT corrective path, ~2-4% of waves,
// execz-skipped otherwise). WR=16 x WC=74 -> 18.9KB/buf, double=37.9KB ->
// 4 blocks/CU (VGPR 108 allows 4). NK drops 6->5 (stg 20 regs).
// Proven pieces kept: corrective hoisted before stg liveness (r10),
// single stg[] prefetch under tap loop (r11), compact (m,dy,dx) metadata.

#define BB 8
#define CC 128
#define HH 64
#define WW 64
#define HWs (HH*WW)
#define KKT 9
#define CH 16              // channels per block
#define NCG (CC/CH)        // 8
#define CPI 4              // channels per LDS float4 cell
#define NIT (CH/CPI)       // 4
#define ROWS 4             // output rows per block
#define NHS (HH/ROWS)      // 16
#define WLO 5              // margin (rows above h0 / cols left of 0)
#define WR  (ROWS+12)      // 16 staged rows: h0-5 .. h0+10
#define CLO 5
#define WC  74             // cols -5 .. 68
#define CELLS (WR*WC)      // 1184 float4 cells = 18.94 KB per buffer
#define NTHR 256
#define NK  ((CELLS + NTHR - 1)/NTHR)   // 5

__global__ __launch_bounds__(NTHR, 2)
void mdcn_kernel(const float* __restrict__ x,
                 const float* __restrict__ offset,
                 const float* __restrict__ mask,
                 const float* __restrict__ dynw,
                 float* __restrict__ out)
{
    __shared__ float4 lds[2][CELLS];

    const int blk = blockIdx.x;
    const int hs = blk & (NHS - 1);
    const int cg = (blk >> 4) & (NCG - 1);
    const int b  = blk >> 7;
    const int tid = threadIdx.x;
    const int w = tid & 63;
    const int h0 = hs * ROWS;
    const int h = h0 + (tid >> 6);

    const float* xg = x + (size_t)(b * CC + cg * CH) * HWs;

    float4 stg[NK];
    #define STAGE_LOAD(XP)                                                    \
    do {                                                                      \
        const float* xp_ = (XP);                                              \
        _Pragma("unroll")                                                     \
        for (int k = 0; k < NK; ++k) {                                        \
            const int idx = tid + k * NTHR;                                   \
            float4 v = make_float4(0.f, 0.f, 0.f, 0.f);                       \
            if (idx < CELLS) {                                                \
                const int row = idx / WC;                                     \
                const int col = idx - row * WC - CLO;                         \
                const int ar  = h0 - WLO + row;                               \
                if ((unsigned)ar < (unsigned)HH &&                            \
                    (unsigned)col < (unsigned)WW) {                           \
                    const float* pp = xp_ + ar * WW + col;                    \
                    v.x = pp[0 * HWs]; v.y = pp[1 * HWs];                     \
                    v.z = pp[2 * HWs]; v.w = pp[3 * HWs];                     \
                }                                                             \
            }                                                                 \
            stg[k] = v;                                                       \
        }                                                                     \
    } while (0)

    #define STAGE_WRITE(DST)                                                  \
    do {                                                                      \
        float4* Lb_ = &lds[DST][0];                                           \
        _Pragma("unroll")                                                     \
        for (int k = 0; k < NK; ++k) {                                        \
            const int idx = tid + k * NTHR;                                   \
            if (idx < CELLS) Lb_[idx] = stg[k];                               \
        }                                                                     \
    } while (0)

    // prologue: stage group 0 into buf0; metadata overlaps load latency
    STAGE_LOAD(xg);

    // ---- per-tap metadata: m, dy, dx + window offset (compact) ----
    float mv[KKT], dyv[KKT], dxv[KKT];
    int   woff[KKT];
    int   badmask = 0;
    const float* offp = offset + (size_t)b * (2 * KKT) * HWs + h * WW + w;
    const float* mskp = mask   + (size_t)b * KKT * HWs       + h * WW + w;
    #pragma unroll
    for (int t = 0; t < KKT; ++t) {
        const float oy = offp[(2 * t)     * HWs];
        const float ox = offp[(2 * t + 1) * HWs];
        const float m  = mskp[t * HWs];
        const float py = (float)(h - 1 + t / 3) + oy;
        const float px = (float)(w - 1 + t % 3) + ox;
        const float fy = floorf(py), fx = floorf(px);
        const int y0 = (int)fy, x0 = (int)fx;
        dyv[t] = py - fy;
        dxv[t] = px - fx;
        const bool inwin = (y0 >= h0 - WLO) && (y0 <= h0 - WLO + WR - 2) &&
                           (x0 >= -CLO)     && (x0 <= -CLO + WC - 2);
        if (!inwin) {
            badmask |= (1 << t);
            woff[t] = 0;
            mv[t] = 0.f;               // zeroes the LDS contribution
        } else {
            woff[t] = (y0 - (h0 - WLO)) * WC + (x0 + CLO);
            mv[t] = m;                 // pads hold zeros -> no corner masks
        }
    }
    const int anybad = __any(badmask != 0);

    STAGE_WRITE(0);
    __syncthreads();

    const float* wtb  = dynw + (size_t)(b * CC + cg * CH) * KKT;
    float*       outp = out  + (size_t)(b * CC + cg * CH) * HWs + h * WW + w;

    for (int it = 0; it < NIT; ++it) {
        const float* wt = wtb + it * CPI * KKT;
        float s0 = 0.f, s1 = 0.f, s2 = 0.f, s3 = 0.f;

        // corrective path FIRST (stg not yet live; execz-skipped at runtime)
        if (anybad) {
            #pragma unroll
            for (int t = 0; t < KKT; ++t) {
                if (badmask & (1 << t)) {
                    const float oy = offp[(2 * t)     * HWs];
                    const float ox = offp[(2 * t + 1) * HWs];
                    const float m  = mskp[t * HWs];
                    const float py = (float)(h - 1 + t / 3) + oy;
                    const float px = (float)(w - 1 + t % 3) + ox;
                    const float fy = floorf(py), fx = floorf(px);
                    const float dy = py - fy, dx = px - fx;
                    const int y0 = (int)fy, x0 = (int)fx;
                    const int y1 = y0 + 1,  x1 = x0 + 1;
                    const int cy0 = min(max(y0, 0), HH - 1);
                    const int cy1 = min(max(y1, 0), HH - 1);
                    const int cx0 = min(max(x0, 0), WW - 1);
                    const int cx1 = min(max(x1, 0), WW - 1);
                    const float m00 = ((unsigned)y0 < HH && (unsigned)x0 < WW) ? 1.f : 0.f;
                    const float m01 = ((unsigned)y0 < HH && (unsigned)x1 < WW) ? 1.f : 0.f;
                    const float m10 = ((unsigned)y1 < HH && (unsigned)x0 < WW) ? 1.f : 0.f;
                    const float m11 = ((unsigned)y1 < HH && (unsigned)x1 < WW) ? 1.f : 0.f;
                    const float omdy = 1.f - dy, omdx = 1.f - dx;
                    #pragma unroll
                    for (int c = 0; c < CPI; ++c) {
                        const float* pl = xg + (size_t)(it * CPI + c) * HWs;
                        const float v = pl[cy0 * WW + cx0] * m00 * (omdy * omdx)
                                      + pl[cy0 * WW + cx1] * m01 * (omdy * dx)
                                      + pl[cy1 * WW + cx0] * m10 * (dy * omdx)
                                      + pl[cy1 * WW + cx1] * m11 * (dy * dx);
                        const float add = v * m * wt[c * KKT + t];
                        if      (c == 0) s0 += add;
                        else if (c == 1) s1 += add;
                        else if (c == 2) s2 += add;
                        else             s3 += add;
                    }
                }
            }
        }

        // prefetch next group (hidden under the tap loop)
        if (it + 1 < NIT) {
            STAGE_LOAD(xg + (size_t)(it + 1) * CPI * HWs);
        }

        const float4* Lp = &lds[it & 1][0];
        #pragma unroll
        for (int t = 0; t < KKT; ++t) {
            const float4 c00 = Lp[woff[t]];
            const float4 c01 = Lp[woff[t] + 1];
            const float4 c10 = Lp[woff[t] + WC];
            const float4 c11 = Lp[woff[t] + WC + 1];
            const float dy = dyv[t], dx = dxv[t], m = mv[t];
            const float omdy = 1.f - dy, omdx = 1.f - dx;
            const float w00 = omdy * omdx * m, w01 = omdy * dx * m;
            const float w10 = dy * omdx * m,   w11 = dy * dx * m;
            const float v0 = c00.x * w00 + c01.x * w01 + c10.x * w10 + c11.x * w11;
            const float v1 = c00.y * w00 + c01.y * w01 + c10.y * w10 + c11.y * w11;
            const float v2 = c00.z * w00 + c01.z * w01 + c10.z * w10 + c11.z * w11;
            const float v3 = c00.w * w00 + c01.w * w01 + c10.w * w10 + c11.w * w11;
            s0 += v0 * wt[0 * KKT + t];
            s1 += v1 * wt[1 * KKT + t];
            s2 += v2 * wt[2 * KKT + t];
            s3 += v3 * wt[3 * KKT + t];
        }

        // write next group into the IDLE buffer (no pre-barrier needed)
        if (it + 1 < NIT) {
            STAGE_WRITE((it + 1) & 1);
        }

        outp[(size_t)(it * CPI + 0) * HWs] = s0;
        outp[(size_t)(it * CPI + 1) * HWs] = s1;
        outp[(size_t)(it * CPI + 2) * HWs] = s2;
        outp[(size_t)(it * CPI + 3) * HWs] = s3;

        if (it + 1 < NIT) {
            __syncthreads();   // writes visible; old buffer free for reuse
        }
    }
    #undef STAGE_LOAD
    #undef STAGE_WRITE
}

extern "C" void kernel_launch(void* const* d_in, const int* in_sizes, int n_in,
                              void* d_out, int out_size, void* d_ws, size_t ws_size,
                              hipStream_t stream) {
    const float* x      = (const float*)d_in[0];
    const float* offset = (const float*)d_in[1];
    const float* mask   = (const float*)d_in[2];
    const float* dynw   = (const float*)d_in[3];
    float* out = (float*)d_out;

    dim3 grid(BB * NCG * NHS);   // 8 * 8 * 16 = 1024 blocks
    dim3 block(NTHR);
    mdcn_kernel<<<grid, block, 0, stream>>>(x, offset, mask, dynw, out);
}